// Round 8
// baseline (8857.368 us; speedup 1.0000x reference)
//
#include <hip/hip_runtime.h>
#include <hip/hip_bf16.h>

#define DT 0.1f
#define TAU_HP 12.3f
#define TAU_LP 2.3f
#define SCAN_B 1024

// Radix-build parameters: bucket = tgt >> BSHIFT (128 targets/bucket).
#define BSHIFT 7
#define BMASK 127
#define BMAX 2048          // max buckets supported (n_neurons <= 262144)
#define CHUNK 32768        // edges per block in hist/bin passes (196 blocks: occupancy)
#define B4_CAP 6144        // max records per bucket in finalize
#define SIM_GRID 768       // persistent sim: 3 blocks/CU worst case, co-resident
#define SIM_B 256

// ---------------------------------------------------------------------------
// R1: atomics removed from steady state via CSR-by-target.
// R2: CSR-vector gather (coalesced, shfl reduce).
// R3: zero-global-atomic radix build (bhist->scan->bin->finalize).
// R4: fused step kernel (double-buffered v), Tm1-target edges dropped.
// R5/R6: edge format experiments; int2 (src|tlow, fp32 w) is best.
// R7 (this): (a) CHUNK back to 32768 (65536 starved occupancy: bin 162us @14%);
//     (b) ONE persistent kernel for all 50 steps w/ software grid barrier
//         (768 blocks, __launch_bounds__(256,4) guarantees co-residency);
//     (c) 16 lanes/row x 2 edges/lane (shorter dependent chain).
// ---------------------------------------------------------------------------

__global__ void init_kernel(float* __restrict__ vA,
                            float* __restrict__ tm1_f,
                            int* __restrict__ bar,
                            int n_neurons, int n_tm1, int steps) {
    int i = blockIdx.x * blockDim.x + threadIdx.x;
    if (i < n_neurons) vA[i] = 0.0f;
    if (i < n_tm1) tm1_f[i] = 0.0f;
    if (i < steps) bar[i] = 0;
}

// --- build pass 1: per-(block,bucket) histogram (Tm1 targets dropped) --------
__global__ void bhist_kernel(const int* __restrict__ tgt, int* __restrict__ blkhist,
                             int n_edges, int n_tm1, int nb, int nblk) {
    __shared__ int hist[BMAX];
    int b = blockIdx.x;
    for (int i = threadIdx.x; i < nb; i += blockDim.x) hist[i] = 0;
    __syncthreads();
    int base = b * CHUNK;
    int end = min(base + CHUNK, n_edges);
    for (int k = base + threadIdx.x; k < end; k += blockDim.x) {
        int t = tgt[k];
        if (t >= n_tm1) atomicAdd(&hist[t >> BSHIFT], 1);
    }
    __syncthreads();
    for (int i = threadIdx.x; i < nb; i += blockDim.x)
        blkhist[(size_t)i * nblk + b] = hist[i];      // bucket-major for scan
}

// --- 3-level exclusive scan --------------------------------------------------
__global__ void scan1_kernel(const int* in, int* out, int* bsums, int n) {
    __shared__ int s[SCAN_B];
    int gid = blockIdx.x * SCAN_B + threadIdx.x;
    int x = (gid < n) ? in[gid] : 0;
    s[threadIdx.x] = x;
    __syncthreads();
    for (int off = 1; off < SCAN_B; off <<= 1) {
        int t = (threadIdx.x >= off) ? s[threadIdx.x - off] : 0;
        __syncthreads();
        s[threadIdx.x] += t;
        __syncthreads();
    }
    if (gid < n) out[gid] = s[threadIdx.x] - x;       // exclusive
    if (threadIdx.x == SCAN_B - 1) bsums[blockIdx.x] = s[SCAN_B - 1];
}

__global__ void scan2_kernel(int* bsums, int nb, int* total) {
    __shared__ int s[SCAN_B];
    int x = (threadIdx.x < nb) ? bsums[threadIdx.x] : 0;
    s[threadIdx.x] = x;
    __syncthreads();
    for (int off = 1; off < SCAN_B; off <<= 1) {
        int t = (threadIdx.x >= off) ? s[threadIdx.x - off] : 0;
        __syncthreads();
        s[threadIdx.x] += t;
        __syncthreads();
    }
    if (threadIdx.x == nb - 1) *total = s[threadIdx.x];   // inclusive grand total
    if (threadIdx.x < nb) bsums[threadIdx.x] = s[threadIdx.x] - x;
}

__global__ void scanadd_kernel(int* data, const int* __restrict__ bsums, int n) {
    int gid = blockIdx.x * blockDim.x + threadIdx.x;
    if (gid < n) data[gid] += bsums[gid / SCAN_B];
}

// --- build pass 2: bin kept edges into bucket order (LDS cursors) ------------
// record = (src | tlow<<18, weight-bits); src < 2^18, tlow 7 bits.
__global__ void bin_kernel(const int* __restrict__ src, const int* __restrict__ tgt,
                           const float* __restrict__ w, const int* __restrict__ scanned,
                           int2* __restrict__ edges, int n_edges, int n_tm1,
                           int nb, int nblk) {
    __shared__ int cur[BMAX];
    int b = blockIdx.x;
    for (int i = threadIdx.x; i < nb; i += blockDim.x)
        cur[i] = scanned[(size_t)i * nblk + b];
    __syncthreads();
    int base = b * CHUNK;
    int end = min(base + CHUNK, n_edges);
    for (int k = base + threadIdx.x; k < end; k += blockDim.x) {
        int t = tgt[k];
        if (t < n_tm1) continue;                      // dead edges (dv[:tm1]=0)
        int pos = atomicAdd(&cur[t >> BSHIFT], 1);    // LDS atomic
        edges[pos] = make_int2(src[k] | ((t & BMASK) << 18), __float_as_int(w[k]));
    }
}

// --- build pass 3: per-bucket finalize, entirely in LDS, in-place ------------
__global__ void finalize_kernel(int2* edges, const int* __restrict__ scanned,
                                int* __restrict__ row_start,
                                const int* __restrict__ total,
                                int n_neurons, int nb, int nblk) {
    __shared__ int2 buf[B4_CAP];
    __shared__ int hist[BMASK + 1], ls[BMASK + 1], cur[BMASK + 1];
    int b = blockIdx.x;
    int n_kept = *total;
    int beg = scanned[(size_t)b * nblk];
    int end = (b == nb - 1) ? n_kept : scanned[(size_t)(b + 1) * nblk];
    int n = min(end - beg, B4_CAP);

    for (int k = threadIdx.x; k < n; k += blockDim.x) buf[k] = edges[beg + k];
    if (threadIdx.x <= BMASK) hist[threadIdx.x] = 0;
    __syncthreads();
    for (int k = threadIdx.x; k < n; k += blockDim.x)
        atomicAdd(&hist[(buf[k].x >> 18) & BMASK], 1);
    __syncthreads();
    if (threadIdx.x <= BMASK) ls[threadIdx.x] = hist[threadIdx.x];
    __syncthreads();
    for (int off = 1; off <= BMASK; off <<= 1) {
        int t = (threadIdx.x <= BMASK && threadIdx.x >= off) ? ls[threadIdx.x - off] : 0;
        __syncthreads();
        if (threadIdx.x <= BMASK) ls[threadIdx.x] += t;   // inclusive
        __syncthreads();
    }
    if (threadIdx.x <= BMASK) {
        int excl = ls[threadIdx.x] - hist[threadIdx.x];
        cur[threadIdx.x] = excl;
        int t = (b << BSHIFT) + threadIdx.x;
        if (t < n_neurons) row_start[t] = beg + excl;
    }
    if (b == nb - 1 && threadIdx.x == 0) row_start[n_neurons] = n_kept;
    __syncthreads();
    for (int k = threadIdx.x; k < n; k += blockDim.x) {
        int2 r = buf[k];
        int pos = atomicAdd(&cur[(r.x >> 18) & BMASK], 1);  // LDS atomic
        edges[beg + pos] = make_int2(r.x & 0x3FFFF, r.y);
    }
}

// --- persistent sim kernel: all steps in one launch --------------------------
// Virtual-tid [0, tm1_pad): Tm1 rows (1 thread/row). [tm1_pad, ...): gather
// rows, 16 lanes/row, 2 edges/lane/iter. Grid barrier (bar[k]) between steps.
// 768 blocks x 256 thr, launch_bounds(256,4) -> >=4 blocks/CU capacity, so all
// 768 are co-resident on 256 CUs (no deadlock).
__global__ __launch_bounds__(SIM_B, 4)
void sim_kernel(const int* __restrict__ row_start,
                const int2* __restrict__ edges,
                float* __restrict__ vA, float* __restrict__ vB,
                float* __restrict__ out,
                float* __restrict__ tm1_f,
                const float* __restrict__ tm1_input,
                const float* __restrict__ tau,
                const float* __restrict__ vrest,
                int* __restrict__ bar,
                int n_neurons, int n_tm1, int tm1_pad,
                int total_threads, int steps) {
    const int gsz = gridDim.x * blockDim.x;
    const int tid0 = blockIdx.x * blockDim.x + threadIdx.x;

    for (int k = 0; k < steps; ++k) {
        const float* vr = (k & 1) ? vB : vA;
        float* vw = (k == steps - 1) ? out : ((k & 1) ? vA : vB);
        const float* x = tm1_input + (size_t)k * n_tm1;
        const bool last = (k == steps - 1);

        for (int tid = tid0; tid < total_threads; tid += gsz) {
            if (tid < tm1_pad) {
                int row = tid;
                if (row < n_tm1) {
                    float cur = vr[row];                 // = tm1_v at step k
                    if (last) {
                        vw[row] = cur;                   // ref: v[:tm1] = old tm1_v
                    } else {
                        float f  = tm1_f[row];
                        float xk = x[row];
                        tm1_f[row] = f + DT * (xk - f) / TAU_HP;
                        vw[row] = cur + DT * (fmaxf(xk - f, 0.0f) - cur) / TAU_LP;
                    }
                }
                continue;
            }
            int t2   = tid - tm1_pad;
            int row  = n_tm1 + (t2 >> 4);
            int lane = t2 & 15;
            int s = row_start[row];
            int e = row_start[row + 1];
            float sum = 0.0f;
            for (int p = (s & ~1) + 2 * lane; p < e; p += 32) {
                int4 q = *(const int4*)(edges + p);      // 16B aligned (p even)
                if (p >= s)    sum += fmaxf(vr[q.x], 0.0f) * __int_as_float(q.y);
                if (p + 1 < e) sum += fmaxf(vr[q.z], 0.0f) * __int_as_float(q.w);
            }
            sum += __shfl_xor(sum, 8);
            sum += __shfl_xor(sum, 4);
            sum += __shfl_xor(sum, 2);
            sum += __shfl_xor(sum, 1);
            if (lane == 0) {
                float vi = vr[row];
                vw[row] = vi + DT * ((-vi + sum + vrest[row]) / tau[row]);
            }
        }

        if (k < steps - 1) {
            // grid-wide barrier: release-add then acquire-spin on bar[k].
            __syncthreads();
            if (threadIdx.x == 0) {
                __threadfence();
                __hip_atomic_fetch_add(&bar[k], 1, __ATOMIC_RELEASE,
                                       __HIP_MEMORY_SCOPE_AGENT);
                while (__hip_atomic_load(&bar[k], __ATOMIC_ACQUIRE,
                                         __HIP_MEMORY_SCOPE_AGENT) < (int)gridDim.x) {
                    __builtin_amdgcn_s_sleep(8);
                }
            }
            __syncthreads();
        }
    }
}

extern "C" void kernel_launch(void* const* d_in, const int* in_sizes, int n_in,
                              void* d_out, int out_size, void* d_ws, size_t ws_size,
                              hipStream_t stream) {
    const float* tm1_input  = (const float*)d_in[0];
    const float* weights    = (const float*)d_in[1];
    const float* tau        = (const float*)d_in[2];
    const float* vrest      = (const float*)d_in[3];
    const int*   source_idx = (const int*)d_in[4];
    const int*   target_idx = (const int*)d_in[5];

    const int n_edges   = in_sizes[1];
    const int n_neurons = in_sizes[2];
    const int n_tm1     = 25000;
    const int steps     = in_sizes[0] / n_tm1;

    const int nb   = (n_neurons + BMASK) >> BSHIFT;          // 1563 buckets
    const int nblk = (n_edges + CHUNK - 1) / CHUNK;          // 196 blocks
    const int n_scan = nb * nblk;                            // 306,348

    // Workspace (4-byte units). edges first -> 16B aligned for int4 gather.
    size_t off = 0;
    auto alloc = [&](size_t n) { size_t o = off; off += n; return o; };
    int* ws_i = (int*)d_ws;
    float* ws_f = (float*)d_ws;

    int2*  edges     = (int2*)(ws_i + alloc((size_t)(n_edges + 8) * 2));
    float* vA        = ws_f + alloc(n_neurons);
    float* vB        = ws_f + alloc(n_neurons);
    float* tm1_f     = ws_f + alloc(n_tm1);
    int*   row_start = ws_i + alloc(n_neurons + 1);
    int*   blkhist   = ws_i + alloc((size_t)n_scan);
    int*   bsums     = ws_i + alloc(SCAN_B);
    int*   total     = ws_i + alloc(1);
    int*   bar       = ws_i + alloc((size_t)steps);
    (void)ws_size;

    float* out = (float*)d_out;

    const int B = 256;
    const int gridN = (n_neurons + B - 1) / B;
    const int nScanBlocks = (n_scan + SCAN_B - 1) / SCAN_B;  // 300 <= 1024
    const int gridSA = (n_scan + B - 1) / B;

    const int tm1_pad = ((n_tm1 + 63) / 64) * 64;            // 25024, wave-aligned
    const int total_threads = tm1_pad + (n_neurons - n_tm1) * 16;

    // --- one-time (per launch) CSR build: zero global atomics ---
    init_kernel<<<gridN, B, 0, stream>>>(vA, tm1_f, bar, n_neurons, n_tm1, steps);
    bhist_kernel<<<nblk, 1024, 0, stream>>>(target_idx, blkhist, n_edges, n_tm1,
                                            nb, nblk);
    scan1_kernel<<<nScanBlocks, SCAN_B, 0, stream>>>(blkhist, blkhist, bsums, n_scan);
    scan2_kernel<<<1, SCAN_B, 0, stream>>>(bsums, nScanBlocks, total);
    scanadd_kernel<<<gridSA, B, 0, stream>>>(blkhist, bsums, n_scan);
    bin_kernel<<<nblk, 1024, 0, stream>>>(source_idx, target_idx, weights, blkhist,
                                          edges, n_edges, n_tm1, nb, nblk);
    finalize_kernel<<<nb, 1024, 0, stream>>>(edges, blkhist, row_start, total,
                                             n_neurons, nb, nblk);

    // --- all 50 steps in ONE persistent launch, double-buffered v ---
    sim_kernel<<<SIM_GRID, SIM_B, 0, stream>>>(
        row_start, edges, vA, vB, out, tm1_f,
        tm1_input, tau, vrest, bar,
        n_neurons, n_tm1, tm1_pad, total_threads, steps);
}

// Round 10
// 7488.624 us; speedup vs baseline: 1.1828x; 1.1828x over previous
//
#include <hip/hip_runtime.h>
#include <hip/hip_bf16.h>

#define DT 0.1f
#define TAU_HP 12.3f
#define TAU_LP 2.3f
#define SCAN_B 1024

// Radix-build parameters: bucket = tgt >> BSHIFT (128 targets/bucket).
#define BSHIFT 7
#define BMASK 127
#define BMAX 2048          // max buckets supported (n_neurons <= 262144)
#define CHUNK 32768        // edges per block in hist/bin passes (196 blocks)
#define B4_CAP 6144        // max records per bucket in finalize
#define SIM_GRID 768       // persistent sim blocks; <= 1024 resident @ 4 blk/CU
#define SIM_B 256

// ---------------------------------------------------------------------------
// R1: atomics removed from steady state via CSR-by-target.
// R2: CSR-vector gather (coalesced, shfl reduce).
// R3: zero-global-atomic radix build (bhist->scan->bin->finalize).
// R4: fused step kernel (double-buffered v), Tm1-target edges dropped.
// R5/R6: edge format: int2 (src|tlow, fp32 w) single stream is best.
// R7: persistent kernel REGRESSED 4.6x: acquire-load inside spin loop emits
//     buffer_inv per poll -> continuous L2 invalidation storm.
// R8: relaxed-spin barrier + static contiguous per-block partitions.
// R9 (this): fix compile — __hip_atomic_fence doesn't exist; use ONE
//     acquire-ordered __hip_atomic_load after the relaxed spin instead.
// ---------------------------------------------------------------------------

__global__ void init_kernel(float* __restrict__ vA,
                            float* __restrict__ tm1_f,
                            int* __restrict__ bar,
                            int n_neurons, int n_tm1, int steps) {
    int i = blockIdx.x * blockDim.x + threadIdx.x;
    if (i < n_neurons) vA[i] = 0.0f;
    if (i < n_tm1) tm1_f[i] = 0.0f;
    if (i < steps) bar[i] = 0;
}

// --- build pass 1: per-(block,bucket) histogram (Tm1 targets dropped) --------
__global__ void bhist_kernel(const int* __restrict__ tgt, int* __restrict__ blkhist,
                             int n_edges, int n_tm1, int nb, int nblk) {
    __shared__ int hist[BMAX];
    int b = blockIdx.x;
    for (int i = threadIdx.x; i < nb; i += blockDim.x) hist[i] = 0;
    __syncthreads();
    int base = b * CHUNK;
    int end = min(base + CHUNK, n_edges);
    for (int k = base + threadIdx.x; k < end; k += blockDim.x) {
        int t = tgt[k];
        if (t >= n_tm1) atomicAdd(&hist[t >> BSHIFT], 1);
    }
    __syncthreads();
    for (int i = threadIdx.x; i < nb; i += blockDim.x)
        blkhist[(size_t)i * nblk + b] = hist[i];      // bucket-major for scan
}

// --- 3-level exclusive scan --------------------------------------------------
__global__ void scan1_kernel(const int* in, int* out, int* bsums, int n) {
    __shared__ int s[SCAN_B];
    int gid = blockIdx.x * SCAN_B + threadIdx.x;
    int x = (gid < n) ? in[gid] : 0;
    s[threadIdx.x] = x;
    __syncthreads();
    for (int off = 1; off < SCAN_B; off <<= 1) {
        int t = (threadIdx.x >= off) ? s[threadIdx.x - off] : 0;
        __syncthreads();
        s[threadIdx.x] += t;
        __syncthreads();
    }
    if (gid < n) out[gid] = s[threadIdx.x] - x;       // exclusive
    if (threadIdx.x == SCAN_B - 1) bsums[blockIdx.x] = s[SCAN_B - 1];
}

__global__ void scan2_kernel(int* bsums, int nb, int* total) {
    __shared__ int s[SCAN_B];
    int x = (threadIdx.x < nb) ? bsums[threadIdx.x] : 0;
    s[threadIdx.x] = x;
    __syncthreads();
    for (int off = 1; off < SCAN_B; off <<= 1) {
        int t = (threadIdx.x >= off) ? s[threadIdx.x - off] : 0;
        __syncthreads();
        s[threadIdx.x] += t;
        __syncthreads();
    }
    if (threadIdx.x == nb - 1) *total = s[threadIdx.x];   // inclusive grand total
    if (threadIdx.x < nb) bsums[threadIdx.x] = s[threadIdx.x] - x;
}

__global__ void scanadd_kernel(int* data, const int* __restrict__ bsums, int n) {
    int gid = blockIdx.x * blockDim.x + threadIdx.x;
    if (gid < n) data[gid] += bsums[gid / SCAN_B];
}

// --- build pass 2: bin kept edges into bucket order (LDS cursors) ------------
// record = (src | tlow<<18, weight-bits); src < 2^18, tlow 7 bits.
__global__ void bin_kernel(const int* __restrict__ src, const int* __restrict__ tgt,
                           const float* __restrict__ w, const int* __restrict__ scanned,
                           int2* __restrict__ edges, int n_edges, int n_tm1,
                           int nb, int nblk) {
    __shared__ int cur[BMAX];
    int b = blockIdx.x;
    for (int i = threadIdx.x; i < nb; i += blockDim.x)
        cur[i] = scanned[(size_t)i * nblk + b];
    __syncthreads();
    int base = b * CHUNK;
    int end = min(base + CHUNK, n_edges);
    for (int k = base + threadIdx.x; k < end; k += blockDim.x) {
        int t = tgt[k];
        if (t < n_tm1) continue;                      // dead edges (dv[:tm1]=0)
        int pos = atomicAdd(&cur[t >> BSHIFT], 1);    // LDS atomic
        edges[pos] = make_int2(src[k] | ((t & BMASK) << 18), __float_as_int(w[k]));
    }
}

// --- build pass 3: per-bucket finalize, entirely in LDS, in-place ------------
__global__ void finalize_kernel(int2* edges, const int* __restrict__ scanned,
                                int* __restrict__ row_start,
                                const int* __restrict__ total,
                                int n_neurons, int nb, int nblk) {
    __shared__ int2 buf[B4_CAP];
    __shared__ int hist[BMASK + 1], ls[BMASK + 1], cur[BMASK + 1];
    int b = blockIdx.x;
    int n_kept = *total;
    int beg = scanned[(size_t)b * nblk];
    int end = (b == nb - 1) ? n_kept : scanned[(size_t)(b + 1) * nblk];
    int n = min(end - beg, B4_CAP);

    for (int k = threadIdx.x; k < n; k += blockDim.x) buf[k] = edges[beg + k];
    if (threadIdx.x <= BMASK) hist[threadIdx.x] = 0;
    __syncthreads();
    for (int k = threadIdx.x; k < n; k += blockDim.x)
        atomicAdd(&hist[(buf[k].x >> 18) & BMASK], 1);
    __syncthreads();
    if (threadIdx.x <= BMASK) ls[threadIdx.x] = hist[threadIdx.x];
    __syncthreads();
    for (int off = 1; off <= BMASK; off <<= 1) {
        int t = (threadIdx.x <= BMASK && threadIdx.x >= off) ? ls[threadIdx.x - off] : 0;
        __syncthreads();
        if (threadIdx.x <= BMASK) ls[threadIdx.x] += t;   // inclusive
        __syncthreads();
    }
    if (threadIdx.x <= BMASK) {
        int excl = ls[threadIdx.x] - hist[threadIdx.x];
        cur[threadIdx.x] = excl;
        int t = (b << BSHIFT) + threadIdx.x;
        if (t < n_neurons) row_start[t] = beg + excl;
    }
    if (b == nb - 1 && threadIdx.x == 0) row_start[n_neurons] = n_kept;
    __syncthreads();
    for (int k = threadIdx.x; k < n; k += blockDim.x) {
        int2 r = buf[k];
        int pos = atomicAdd(&cur[(r.x >> 18) & BMASK], 1);  // LDS atomic
        edges[beg + pos] = make_int2(r.x & 0x3FFFF, r.y);
    }
}

// --- persistent sim kernel: all steps in one launch --------------------------
// Block b owns virtual tids [b*chunkT, min((b+1)*chunkT, total)) processed with
// block-stride 256 (contiguous -> L2 locality). tid < tm1_pad: Tm1 rows.
// Else: gather rows, 16 lanes/row, 2 edges/lane/iter. chunkT % 256 == 0 and
// tm1_pad % 64 == 0 keep the 16-lane shfl groups aligned to physical lanes.
__global__ __launch_bounds__(SIM_B, 4)
void sim_kernel(const int* __restrict__ row_start,
                const int2* __restrict__ edges,
                float* __restrict__ vA, float* __restrict__ vB,
                float* __restrict__ out,
                float* __restrict__ tm1_f,
                const float* __restrict__ tm1_input,
                const float* __restrict__ tau,
                const float* __restrict__ vrest,
                int* __restrict__ bar,
                int n_neurons, int n_tm1, int tm1_pad,
                int total_threads, int chunkT, int steps) {
    const int base = blockIdx.x * chunkT;
    const int bend = min(base + chunkT, total_threads);

    for (int k = 0; k < steps; ++k) {
        const float* vr = (k & 1) ? vB : vA;
        float* vw = (k == steps - 1) ? out : ((k & 1) ? vA : vB);
        const float* x = tm1_input + (size_t)k * n_tm1;
        const bool last = (k == steps - 1);

        for (int tid = base + (int)threadIdx.x; tid < bend; tid += SIM_B) {
            if (tid < tm1_pad) {
                int row = tid;
                if (row < n_tm1) {
                    float cur = vr[row];                 // = tm1_v at step k
                    if (last) {
                        vw[row] = cur;                   // ref: v[:tm1] = old tm1_v
                    } else {
                        float f  = tm1_f[row];
                        float xk = x[row];
                        tm1_f[row] = f + DT * (xk - f) / TAU_HP;
                        vw[row] = cur + DT * (fmaxf(xk - f, 0.0f) - cur) / TAU_LP;
                    }
                }
                continue;
            }
            int t2   = tid - tm1_pad;
            int row  = n_tm1 + (t2 >> 4);
            int lane = t2 & 15;
            int s = row_start[row];
            int e = row_start[row + 1];
            float sum = 0.0f;
            for (int p = (s & ~1) + 2 * lane; p < e; p += 32) {
                int4 q = *(const int4*)(edges + p);      // 16B aligned (p even)
                if (p >= s)    sum += fmaxf(vr[q.x], 0.0f) * __int_as_float(q.y);
                if (p + 1 < e) sum += fmaxf(vr[q.z], 0.0f) * __int_as_float(q.w);
            }
            sum += __shfl_xor(sum, 8);
            sum += __shfl_xor(sum, 4);
            sum += __shfl_xor(sum, 2);
            sum += __shfl_xor(sum, 1);
            if (lane == 0) {
                float vi = vr[row];
                vw[row] = vi + DT * ((-vi + sum + vrest[row]) / tau[row]);
            }
        }

        if (k < steps - 1) {
            __syncthreads();
            if (threadIdx.x == 0) {
                __threadfence();                          // release: L2 writeback
                __hip_atomic_fetch_add(&bar[k], 1, __ATOMIC_RELAXED,
                                       __HIP_MEMORY_SCOPE_AGENT);
                while (__hip_atomic_load(&bar[k], __ATOMIC_RELAXED,
                                         __HIP_MEMORY_SCOPE_AGENT) < (int)gridDim.x) {
                    __builtin_amdgcn_s_sleep(2);          // relaxed poll: no inv
                }
                // ONE acquire-ordered op per step: makes other XCDs' writes
                // visible (single buffer_inv, not per-poll).
                (void)__hip_atomic_load(&bar[k], __ATOMIC_ACQUIRE,
                                        __HIP_MEMORY_SCOPE_AGENT);
            }
            __syncthreads();
        }
    }
}

extern "C" void kernel_launch(void* const* d_in, const int* in_sizes, int n_in,
                              void* d_out, int out_size, void* d_ws, size_t ws_size,
                              hipStream_t stream) {
    const float* tm1_input  = (const float*)d_in[0];
    const float* weights    = (const float*)d_in[1];
    const float* tau        = (const float*)d_in[2];
    const float* vrest      = (const float*)d_in[3];
    const int*   source_idx = (const int*)d_in[4];
    const int*   target_idx = (const int*)d_in[5];

    const int n_edges   = in_sizes[1];
    const int n_neurons = in_sizes[2];
    const int n_tm1     = 25000;
    const int steps     = in_sizes[0] / n_tm1;

    const int nb   = (n_neurons + BMASK) >> BSHIFT;          // 1563 buckets
    const int nblk = (n_edges + CHUNK - 1) / CHUNK;          // 196 blocks
    const int n_scan = nb * nblk;                            // 306,348

    // Workspace (4-byte units). edges first -> 16B aligned for int4 gather.
    size_t off = 0;
    auto alloc = [&](size_t n) { size_t o = off; off += n; return o; };
    int* ws_i = (int*)d_ws;
    float* ws_f = (float*)d_ws;

    int2*  edges     = (int2*)(ws_i + alloc((size_t)(n_edges + 8) * 2));
    float* vA        = ws_f + alloc(n_neurons);
    float* vB        = ws_f + alloc(n_neurons);
    float* tm1_f     = ws_f + alloc(n_tm1);
    int*   row_start = ws_i + alloc(n_neurons + 1);
    int*   blkhist   = ws_i + alloc((size_t)n_scan);
    int*   bsums     = ws_i + alloc(SCAN_B);
    int*   total     = ws_i + alloc(1);
    int*   bar       = ws_i + alloc((size_t)steps);
    (void)ws_size;

    float* out = (float*)d_out;

    const int B = 256;
    const int gridN = (n_neurons + B - 1) / B;
    const int nScanBlocks = (n_scan + SCAN_B - 1) / SCAN_B;  // 300 <= 1024
    const int gridSA = (n_scan + B - 1) / B;

    const int tm1_pad = ((n_tm1 + 63) / 64) * 64;            // 25024, wave-aligned
    const int total_threads = tm1_pad + (n_neurons - n_tm1) * 16;
    const int chunkT = (((total_threads + SIM_GRID - 1) / SIM_GRID + SIM_B - 1)
                        / SIM_B) * SIM_B;                    // per-block span, %256==0

    // --- one-time (per launch) CSR build: zero global atomics ---
    init_kernel<<<gridN, B, 0, stream>>>(vA, tm1_f, bar, n_neurons, n_tm1, steps);
    bhist_kernel<<<nblk, 1024, 0, stream>>>(target_idx, blkhist, n_edges, n_tm1,
                                            nb, nblk);
    scan1_kernel<<<nScanBlocks, SCAN_B, 0, stream>>>(blkhist, blkhist, bsums, n_scan);
    scan2_kernel<<<1, SCAN_B, 0, stream>>>(bsums, nScanBlocks, total);
    scanadd_kernel<<<gridSA, B, 0, stream>>>(blkhist, bsums, n_scan);
    bin_kernel<<<nblk, 1024, 0, stream>>>(source_idx, target_idx, weights, blkhist,
                                          edges, n_edges, n_tm1, nb, nblk);
    finalize_kernel<<<nb, 1024, 0, stream>>>(edges, blkhist, row_start, total,
                                             n_neurons, nb, nblk);

    // --- all 50 steps in ONE persistent launch, double-buffered v ---
    sim_kernel<<<SIM_GRID, SIM_B, 0, stream>>>(
        row_start, edges, vA, vB, out, tm1_f,
        tm1_input, tau, vrest, bar,
        n_neurons, n_tm1, tm1_pad, total_threads, chunkT, steps);
}